// Round 2
// baseline (335.981 us; speedup 1.0000x reference)
//
#include <hip/hip_runtime.h>

// Problem constants
#define N_PTS   65536      // B*H*W = 64*32*32
#define K_CODES 1024
#define C_DIM   64
#define HW      1024
#define Q_ELEMS 4194304

// d_out layout (float32): [vq_loss(1) | quantized(4194304) | perplexity(1) | indices(65536)]
#define OUT_Q_OFF 1
#define OUT_P_OFF 4194305
#define OUT_I_OFF 4194306

// ws layout (bytes)
#define WS_HIST 0          // 1024 u32    (4096)
#define WS_SSE  4096       // 1 double    (8)
#define WS_DONE 4104       // 1 u32       (4)
#define WS_CSUM 8192       // 1024 f32    (4096)
#define WS_CBP  16384      // packed A-frags: 32 tiles * 9 slots * 512 shorts = 294912 B

// Screen metric is w = x.c - csum/2 (argmin dist == argmax w). Proven dist-space
// thresholds EPS_A=1.5e-4 / EPS_T=4e-4 map to w-space /2:
#define EPS_A_W 7.5e-5f    // ambiguous if m2 >= m1 - EPS_A_W
#define EPS_T_W 2.0e-4f    // candidate tile if tmax >= m1 - EPS_T_W

#define PTS_BLK 64         // points per block (64 pts, 4 waves, 1024 blocks)

typedef float f32x16 __attribute__((ext_vector_type(16)));
typedef short bf16x8 __attribute__((ext_vector_type(8)));

__device__ __forceinline__ unsigned short bf16rn(float f) {
    unsigned int u = __float_as_uint(f);
    return (unsigned short)((u + 0x7FFFu + ((u >> 16) & 1u)) >> 16);
}
__device__ __forceinline__ float bf16tof(unsigned short h) {
    return __uint_as_float(((unsigned int)h) << 16);
}

// numpy pairwise sum (n=64): 8 accumulators striding 8, then pairwise combine.
__device__ __forceinline__ float np_pairwise_sumsq64(const float* a) {
    float r[8];
    #pragma unroll
    for (int j = 0; j < 8; ++j) r[j] = __fmul_rn(a[j], a[j]);
    #pragma unroll
    for (int i = 8; i < 64; i += 8) {
        #pragma unroll
        for (int j = 0; j < 8; ++j)
            r[j] = __fadd_rn(r[j], __fmul_rn(a[i + j], a[i + j]));
    }
    return __fadd_rn(__fadd_rn(__fadd_rn(r[0], r[1]), __fadd_rn(r[2], r[3])),
                     __fadd_rn(__fadd_rn(r[4], r[5]), __fadd_rn(r[6], r[7])));
}

// Prep (2048 threads): csum + codebook packed into MFMA A-frag order.
// Also zeroes hist/sse/done (kernel boundary publishes before vq_main).
__global__ void vq_prep(const float* __restrict__ cb, float* __restrict__ csum,
                        unsigned short* __restrict__ cbp,
                        unsigned int* __restrict__ hist,
                        double* __restrict__ sse,
                        unsigned int* __restrict__ done) {
    int g = blockIdx.x * 256 + threadIdx.x;   // 0..2047
    if (g < 1024) hist[g] = 0u;
    if (g == 1024) { *sse = 0.0; *done = 0u; }
    int t = g >> 6, lane = g & 63, l31 = lane & 31, half = lane >> 5;
    int row = t * 32 + l31;
    const float* r = cb + row * 64;
    float cs = np_pairwise_sumsq64(r);
    if (half == 0) csum[row] = cs;
    size_t tb = (size_t)t * 9 * 512;          // shorts per tile
    #pragma unroll
    for (int c = 0; c < 4; ++c) {
        bf16x8 h8, l8;
        #pragma unroll
        for (int j = 0; j < 8; ++j) {
            float f = r[c * 16 + half * 8 + j];
            unsigned short h = bf16rn(f);
            h8[j] = (short)h;
            l8[j] = (short)bf16rn(f - bf16tof(h));
        }
        *(bf16x8*)(cbp + tb + (size_t)(c * 2 + 0) * 512 + lane * 8) = h8;
        *(bf16x8*)(cbp + tb + (size_t)(c * 2 + 1) * 512 + lane * 8) = l8;
    }
    bf16x8 c8;
    #pragma unroll
    for (int j = 0; j < 8; ++j) c8[j] = 0;
    if (half == 0) c8[0] = (short)bf16rn(-0.5f * cs);
    *(bf16x8*)(cbp + tb + (size_t)8 * 512 + lane * 8) = c8;
}

// Main: block = 64 points, 4 waves (256 thr). Wave = (point-group, tile-half):
// grp = wave>>1 owns 32 points, thalf = wave&1 screens tiles [thalf*16, +16).
// Grid = 1024 blocks => 4 blocks/CU x 4 waves = 16 waves/CU (4/SIMD) WITHOUT
// capping VGPRs below the natural ~88 allocation (R1's (512,4) clamp to 64
// VGPRs spilled tile buffers to scratch: FETCH 10.5->176 MB, 281 us).
// Screen: ONE MFMA accumulator (csum bias + hi*hi + hi*lo + lo*hi; reorder
// error ~5e-8 << EPS_A_W) + med3-based top-2 (all validated in R1, passed).
// Last block finalizes perplexity/loss (threadfence+counter; agent-scope loads).
__global__ __launch_bounds__(256, 4) void vq_main(
        const float* __restrict__ latents,
        const float* __restrict__ cb,
        const float* __restrict__ csum,
        const unsigned short* __restrict__ cbp,
        unsigned int* __restrict__ hist,
        double* __restrict__ sse,
        unsigned int* __restrict__ done,
        float* __restrict__ out) {
    __shared__ float xs[PTS_BLK * 65];        // 16.3 KB, stride 65 (x, then q)
    __shared__ float tmax[32 * PTS_BLK];      // 8 KB per-(tile,point) screen max
    __shared__ float m1s[4 * 32], m2s[4 * 32];
    __shared__ int   i1s[4 * 32];
    __shared__ float m1f[PTS_BLK];
    __shared__ int   fk[PTS_BLK], ambig[PTS_BLK], acount;
    __shared__ double wred[4];
    __shared__ int isLast;

    const int tid  = threadIdx.x;
    const int lane = tid & 63, wave = tid >> 6;   // wave 0..3
    const int grp = wave >> 1, thalf = wave & 1;
    const int n0 = blockIdx.x * PTS_BLK;
    const int b = n0 >> 10, hw0 = n0 & 1023;
    const float* xg = latents + (size_t)b * C_DIM * HW + hw0;

    for (int i = tid; i < PTS_BLK * 64; i += 256) {
        int p = i & (PTS_BLK - 1), d = i >> 6;
        xs[p * 65 + d] = xg[(size_t)d * HW + p];
    }
    if (tid == 0) acount = 0;
    __syncthreads();

    // B-frags: col = lane&31 -> point, k = (lane>>5)*8 + j
    const int l31 = lane & 31, half = lane >> 5;
    const int pb = (grp << 5) + l31;
    bf16x8 xh[4], xl[4], x4;
    #pragma unroll
    for (int c = 0; c < 4; ++c)
        #pragma unroll
        for (int j = 0; j < 8; ++j) {
            float f = xs[pb * 65 + c * 16 + half * 8 + j];
            unsigned short h = bf16rn(f);
            xh[c][j] = (short)h;
            xl[c][j] = (short)bf16rn(f - bf16tof(h));
        }
    #pragma unroll
    for (int j = 0; j < 8; ++j) x4[j] = 0;
    if (half == 0) x4[0] = (short)0x3F80;     // bf16(1.0) at k=64

    float m1 = -3e38f, m2 = -3e38f;
    int i1 = 0;
    const int RC[16] = {0,1,2,3,8,9,10,11,16,17,18,19,24,25,26,27};
    const int rh4 = half * 4;
    const bf16x8* base = (const bf16x8*)cbp;

    auto load_tile = [&](int t, bf16x8* ch, bf16x8* cl, bf16x8& ca) {
        const bf16x8* bp = base + (size_t)t * 576 + lane;
        #pragma unroll
        for (int c = 0; c < 4; ++c) {
            ch[c] = bp[c * 128];
            cl[c] = bp[c * 128 + 64];
        }
        ca = bp[512];
    };
    auto screen_tile = [&](int t, const bf16x8* ch, const bf16x8* cl, bf16x8 ca) {
        f32x16 acc;
        #pragma unroll
        for (int r = 0; r < 16; ++r) acc[r] = 0.0f;
        // single accumulator: csum bias + hi*hi + hi*lo + lo*hi
        acc = __builtin_amdgcn_mfma_f32_32x32x16_bf16(ca, x4, acc, 0, 0, 0);
        #pragma unroll
        for (int c = 0; c < 4; ++c)
            acc = __builtin_amdgcn_mfma_f32_32x32x16_bf16(ch[c], xh[c], acc, 0, 0, 0);
        #pragma unroll
        for (int c = 0; c < 4; ++c)
            acc = __builtin_amdgcn_mfma_f32_32x32x16_bf16(ch[c], xl[c], acc, 0, 0, 0);
        #pragma unroll
        for (int c = 0; c < 4; ++c)
            acc = __builtin_amdgcn_mfma_f32_32x32x16_bf16(cl[c], xh[c], acc, 0, 0, 0);
        // within-tile top-2 + first-argmax: 4 VALU/value (med3, cmp, cnd, fmax)
        float vl = -3e38f, sl = -3e38f;
        int kl = 0;
        #pragma unroll
        for (int r = 0; r < 16; ++r) {
            float v = acc[r];
            sl = __builtin_amdgcn_fmed3f(v, sl, vl);   // = max(sl, min(vl_old, v))
            bool c2 = v > vl;                           // strict >: first-max
            kl = c2 ? RC[r] : kl;                       // inline-const cndmask
            vl = fmaxf(vl, v);
        }
        // per-tile merge into global (m1, m2, i1) — comparison-exact
        int k = (t << 5) + rh4 + kl;
        bool cg = vl > m1;                              // strict: earlier tile wins ties
        i1 = cg ? k : i1;
        float X = cg ? sl : m2;
        m2 = __builtin_amdgcn_fmed3f(vl, X, m1);        // = max(min(m1,vl), X)
        m1 = fmaxf(m1, vl);
        float tlm = fmaxf(vl, __shfl_xor(vl, 32, 64));
        if (half == 0) tmax[t * PTS_BLK + pb] = tlm;
    };

    bf16x8 chA[4], clA[4], caA, chB[4], clB[4], caB;
    const int t0 = thalf << 4;
    load_tile(t0, chA, clA, caA);
    for (int t = t0; t < t0 + 16; t += 2) {   // double-buffered tile loop
        load_tile(t + 1, chB, clB, caB);
        screen_tile(t, chA, clA, caA);
        if (t + 2 < t0 + 16) load_tile(t + 2, chA, clA, caA);
        screen_tile(t + 1, chB, clB, caB);
    }
    // cross-half merge; ties resolve via ambiguous path
    {
        float m1o = __shfl_xor(m1, 32, 64);
        float m2o = __shfl_xor(m2, 32, 64);
        int   i1o = __shfl_xor(i1, 32, 64);
        m2 = fmaxf(fmaxf(m2, m2o), fminf(m1, m1o));
        i1 = (m1o > m1) ? i1o : i1;
        m1 = fmaxf(m1, m1o);
        if (half == 0) {
            m1s[wave * 32 + l31] = m1;
            m2s[wave * 32 + l31] = m2;
            i1s[wave * 32 + l31] = i1;
        }
    }
    __syncthreads();
    // wave-pair merge: top-2 of union; wave A (lower tiles) wins ties -> lower k
    if (tid < PTS_BLK) {
        int p = tid, l = p & 31, wA = (p >> 5) * 2;
        float a1 = m1s[wA * 32 + l], a2 = m2s[wA * 32 + l];
        float b1 = m1s[wA * 32 + 32 + l], b2 = m2s[wA * 32 + 32 + l];
        int   ai = i1s[wA * 32 + l],  bi = i1s[wA * 32 + 32 + l];
        bool cg = b1 > a1;
        float mm1 = fmaxf(a1, b1);
        float mm2 = __builtin_amdgcn_fmed3f(a1, b1, cg ? b2 : a2);
        m1f[p] = mm1;
        fk[p]  = cg ? bi : ai;
        if (mm2 >= mm1 - EPS_A_W) {
            int a = atomicAdd(&acount, 1);
            ambig[a] = p;
        }
    }
    __syncthreads();

    // Exact rescan: one wave per ambiguous point, candidate tiles only.
    // Reference-bit-exact: dist = fl32(fl32(A+csum[k]) - fl32(2*seqFMA)).
    for (int a = wave; a < acount; a += 4) {
        int p = ambig[a];
        const float* xrow = &xs[p * 65];
        float Aq = np_pairwise_sumsq64(xrow);
        float thr = m1f[p] - EPS_T_W;
        unsigned long long best = ~0ULL;
        for (int t = 0; t < 32; ++t) {
            if (tmax[t * PTS_BLK + p] < thr) continue;   // wave-uniform branch
            if (lane < 32) {
                int k = (t << 5) + lane;
                const float* crow = cb + (size_t)k * 64;
                float m = 0.0f;
                #pragma unroll
                for (int d = 0; d < 64; ++d) m = __fmaf_rn(xrow[d], crow[d], m);
                float D = __fsub_rn(__fadd_rn(Aq, csum[k]), __fmul_rn(2.0f, m));
                unsigned long long key =
                    ((unsigned long long)__float_as_uint(D) << 10) | (unsigned)k;
                best = (key < best) ? key : best;
            }
        }
        #pragma unroll
        for (int off = 32; off > 0; off >>= 1) {
            unsigned long long o = __shfl_xor(best, off, 64);
            best = (o < best) ? o : best;
        }
        if (lane == 0) fk[p] = (int)(best & 1023ULL);
    }
    __syncthreads();

    // indices + histogram
    if (tid < PTS_BLK) {
        int myk = fk[tid];
        out[OUT_I_OFF + n0 + tid] = (float)myk;
        atomicAdd(&hist[myk], 1u);
    }
    // Fused stage+SSE: read each selected cb row ONCE row-coalesced (float4),
    // accumulate f64 SSE against x in xs, overwrite xs with q for write-out.
    double e = 0.0;
    #pragma unroll
    for (int i2 = 0; i2 < 4; ++i2) {
        int i = tid + i2 * 256;               // 0..1023
        int p = i >> 4, seg = i & 15;
        const float4 q = *(const float4*)(cb + (size_t)fk[p] * 64 + seg * 4);
        float* xp = &xs[p * 65 + seg * 4];    // stride-65: only 4B aligned -> scalar ops
        float x0 = xp[0], x1 = xp[1], x2 = xp[2], x3 = xp[3];
        double d0 = (double)x0 - (double)q.x; e = fma(d0, d0, e);
        double d1 = (double)x1 - (double)q.y; e = fma(d1, d1, e);
        double d2 = (double)x2 - (double)q.z; e = fma(d2, d2, e);
        double d3 = (double)x3 - (double)q.w; e = fma(d3, d3, e);
        xp[0] = q.x; xp[1] = q.y; xp[2] = q.z; xp[3] = q.w;
    }
    #pragma unroll
    for (int off = 32; off > 0; off >>= 1) e += __shfl_down(e, off, 64);
    if (lane == 0) wred[wave] = e;
    __syncthreads();
    if (tid == 0) {
        double s = 0.0;
        #pragma unroll
        for (int w = 0; w < 4; ++w) s += wred[w];
        atomicAdd(sse, s);
    }
    // quantized [B,C,H,W]: coalesced 64-float store rows per c, from staged xs
    for (int i = tid; i < PTS_BLK * 64; i += 256) {
        int p = i & (PTS_BLK - 1), c = i >> 6;
        out[OUT_Q_OFF + (size_t)b * 65536 + (size_t)c * HW + hw0 + p] = xs[p * 65 + c];
    }

    // Last-block finalize (replaces vq_final kernel): release via threadfence,
    // count blocks, winner reads hist/sse with agent-scope atomic loads
    // (cross-XCD L2s are not coherent for plain loads).
    __threadfence();
    __syncthreads();
    if (tid == 0)
        isLast = (atomicAdd(done, 1u) == (unsigned)(gridDim.x - 1)) ? 1 : 0;
    __syncthreads();
    if (isLast) {
        double s = 0.0;
        for (int i = tid; i < K_CODES; i += 256) {
            unsigned int h = __hip_atomic_load(&hist[i], __ATOMIC_RELAXED,
                                               __HIP_MEMORY_SCOPE_AGENT);
            double pr = (double)h / (double)N_PTS;
            s += pr * log(pr + 1e-10);
        }
        #pragma unroll
        for (int off = 32; off > 0; off >>= 1) s += __shfl_down(s, off, 64);
        if (lane == 0) wred[wave] = s;
        __syncthreads();
        if (tid == 0) {
            double st = 0.0;
            #pragma unroll
            for (int w = 0; w < 4; ++w) st += wred[w];
            double sv = __hip_atomic_load(sse, __ATOMIC_RELAXED,
                                          __HIP_MEMORY_SCOPE_AGENT);
            out[OUT_P_OFF] = (float)exp(-st);
            out[0] = (float)(1.25 * sv / (double)Q_ELEMS);
        }
    }
}

extern "C" void kernel_launch(void* const* d_in, const int* in_sizes, int n_in,
                              void* d_out, int out_size, void* d_ws, size_t ws_size,
                              hipStream_t stream) {
    const float* latents = (const float*)d_in[0];
    const float* cb      = (const float*)d_in[1];
    float* out = (float*)d_out;
    char* ws = (char*)d_ws;

    unsigned int*   hist = (unsigned int*)(ws + WS_HIST);
    double*         sse  = (double*)(ws + WS_SSE);
    unsigned int*   done = (unsigned int*)(ws + WS_DONE);
    float*          csum = (float*)(ws + WS_CSUM);
    unsigned short* cbp  = (unsigned short*)(ws + WS_CBP);

    vq_prep<<<8, 256, 0, stream>>>(cb, csum, cbp, hist, sse, done);
    vq_main<<<N_PTS / PTS_BLK, 256, 0, stream>>>(latents, cb, csum, cbp,
                                                 hist, sse, done, out);
}

// Round 3
// 237.774 us; speedup vs baseline: 1.4130x; 1.4130x over previous
//
#include <hip/hip_runtime.h>

// Problem constants
#define N_PTS   65536      // B*H*W = 64*32*32
#define K_CODES 1024
#define C_DIM   64
#define HW      1024
#define Q_ELEMS 4194304

// d_out layout (float32): [vq_loss(1) | quantized(4194304) | perplexity(1) | indices(65536)]
#define OUT_Q_OFF 1
#define OUT_P_OFF 4194305
#define OUT_I_OFF 4194306

// ws layout (bytes)
#define WS_HIST 0          // 1024 u32    (4096)
#define WS_SSE  4096       // 1 double    (8)
#define WS_DONE 4104       // 1 u32       (4)
#define WS_CSUM 8192       // 1024 f32    (4096)
#define WS_CBP  16384      // packed A-frags: 32 tiles * 9 slots * 512 shorts = 294912 B

// Screen metric is w = x.c - csum/2 (argmin dist == argmax w). Proven dist-space
// thresholds EPS_A=1.5e-4 / EPS_T=4e-4 map to w-space /2:
#define EPS_A_W 7.5e-5f    // ambiguous if m2 >= m1 - EPS_A_W
#define EPS_T_W 2.0e-4f    // candidate tile if tmax >= m1 - EPS_T_W

#define PTS_BLK 64         // points per block (64 pts, 4 waves, 1024 blocks)

typedef float f32x16 __attribute__((ext_vector_type(16)));
typedef short bf16x8 __attribute__((ext_vector_type(8)));

__device__ __forceinline__ unsigned short bf16rn(float f) {
    unsigned int u = __float_as_uint(f);
    return (unsigned short)((u + 0x7FFFu + ((u >> 16) & 1u)) >> 16);
}
__device__ __forceinline__ float bf16tof(unsigned short h) {
    return __uint_as_float(((unsigned int)h) << 16);
}

// numpy pairwise sum (n=64): 8 accumulators striding 8, then pairwise combine.
__device__ __forceinline__ float np_pairwise_sumsq64(const float* a) {
    float r[8];
    #pragma unroll
    for (int j = 0; j < 8; ++j) r[j] = __fmul_rn(a[j], a[j]);
    #pragma unroll
    for (int i = 8; i < 64; i += 8) {
        #pragma unroll
        for (int j = 0; j < 8; ++j)
            r[j] = __fadd_rn(r[j], __fmul_rn(a[i + j], a[i + j]));
    }
    return __fadd_rn(__fadd_rn(__fadd_rn(r[0], r[1]), __fadd_rn(r[2], r[3])),
                     __fadd_rn(__fadd_rn(r[4], r[5]), __fadd_rn(r[6], r[7])));
}

// Prep (2048 threads): csum + codebook packed into MFMA A-frag order.
// Also zeroes hist/sse/done (kernel boundary publishes before vq_main).
__global__ void vq_prep(const float* __restrict__ cb, float* __restrict__ csum,
                        unsigned short* __restrict__ cbp,
                        unsigned int* __restrict__ hist,
                        double* __restrict__ sse,
                        unsigned int* __restrict__ done) {
    int g = blockIdx.x * 256 + threadIdx.x;   // 0..2047
    if (g < 1024) hist[g] = 0u;
    if (g == 1024) { *sse = 0.0; *done = 0u; }
    int t = g >> 6, lane = g & 63, l31 = lane & 31, half = lane >> 5;
    int row = t * 32 + l31;
    const float* r = cb + row * 64;
    float cs = np_pairwise_sumsq64(r);
    if (half == 0) csum[row] = cs;
    size_t tb = (size_t)t * 9 * 512;          // shorts per tile
    #pragma unroll
    for (int c = 0; c < 4; ++c) {
        bf16x8 h8, l8;
        #pragma unroll
        for (int j = 0; j < 8; ++j) {
            float f = r[c * 16 + half * 8 + j];
            unsigned short h = bf16rn(f);
            h8[j] = (short)h;
            l8[j] = (short)bf16rn(f - bf16tof(h));
        }
        *(bf16x8*)(cbp + tb + (size_t)(c * 2 + 0) * 512 + lane * 8) = h8;
        *(bf16x8*)(cbp + tb + (size_t)(c * 2 + 1) * 512 + lane * 8) = l8;
    }
    bf16x8 c8;
    #pragma unroll
    for (int j = 0; j < 8; ++j) c8[j] = 0;
    if (half == 0) c8[0] = (short)bf16rn(-0.5f * cs);
    *(bf16x8*)(cbp + tb + (size_t)8 * 512 + lane * 8) = c8;
}

// Main: block = 64 points, 4 waves (256 thr). Wave = (point-group, tile-half):
// grp = wave>>1 owns 32 points, thalf = wave&1 screens tiles [thalf*16, +16).
// Grid = 1024 blocks => 4 blocks/CU x 4 waves = 16 waves/CU by construction.
// launch_bounds MUST be (256,2): measured gfx950 arch-VGPR cap = 256/min_waves
// ((256,2)->88 VGPR no spill @R0; (256,4)/(512,4)->64 VGPR, tile frags spill,
// FETCH 10.5->180 MB, 4x slower @R1/R2). Occupancy comes from grid+LDS shape
// (27.6 KB -> 5 blocks/CU LDS-wise), NOT from the launch-bounds knob.
// Screen: ONE MFMA accumulator (csum bias + hi*hi + hi*lo + lo*hi; reorder
// error ~5e-8 << EPS_A_W) + med3-based top-2 (validated R1/R2, passed).
// Last block finalizes perplexity/loss (threadfence+counter; agent-scope loads).
__global__ __launch_bounds__(256, 2) void vq_main(
        const float* __restrict__ latents,
        const float* __restrict__ cb,
        const float* __restrict__ csum,
        const unsigned short* __restrict__ cbp,
        unsigned int* __restrict__ hist,
        double* __restrict__ sse,
        unsigned int* __restrict__ done,
        float* __restrict__ out) {
    __shared__ float xs[PTS_BLK * 65];        // 16.3 KB, stride 65 (x, then q)
    __shared__ float tmax[32 * PTS_BLK];      // 8 KB per-(tile,point) screen max
    __shared__ float m1s[4 * 32], m2s[4 * 32];
    __shared__ int   i1s[4 * 32];
    __shared__ float m1f[PTS_BLK];
    __shared__ int   fk[PTS_BLK], ambig[PTS_BLK], acount;
    __shared__ double wred[4];
    __shared__ int isLast;

    const int tid  = threadIdx.x;
    const int lane = tid & 63, wave = tid >> 6;   // wave 0..3
    const int grp = wave >> 1, thalf = wave & 1;
    const int n0 = blockIdx.x * PTS_BLK;
    const int b = n0 >> 10, hw0 = n0 & 1023;
    const float* xg = latents + (size_t)b * C_DIM * HW + hw0;

    for (int i = tid; i < PTS_BLK * 64; i += 256) {
        int p = i & (PTS_BLK - 1), d = i >> 6;
        xs[p * 65 + d] = xg[(size_t)d * HW + p];
    }
    if (tid == 0) acount = 0;
    __syncthreads();

    // B-frags: col = lane&31 -> point, k = (lane>>5)*8 + j
    const int l31 = lane & 31, half = lane >> 5;
    const int pb = (grp << 5) + l31;
    bf16x8 xh[4], xl[4], x4;
    #pragma unroll
    for (int c = 0; c < 4; ++c)
        #pragma unroll
        for (int j = 0; j < 8; ++j) {
            float f = xs[pb * 65 + c * 16 + half * 8 + j];
            unsigned short h = bf16rn(f);
            xh[c][j] = (short)h;
            xl[c][j] = (short)bf16rn(f - bf16tof(h));
        }
    #pragma unroll
    for (int j = 0; j < 8; ++j) x4[j] = 0;
    if (half == 0) x4[0] = (short)0x3F80;     // bf16(1.0) at k=64

    // loop-invariant zero C-operand: first MFMA of each tile reads ZERO and
    // fully overwrites acc -> no per-tile 16-mov zero-init.
    f32x16 zacc;
    #pragma unroll
    for (int r = 0; r < 16; ++r) zacc[r] = 0.0f;

    float m1 = -3e38f, m2 = -3e38f;
    int i1 = 0;
    const int RC[16] = {0,1,2,3,8,9,10,11,16,17,18,19,24,25,26,27};
    const int rh4 = half * 4;
    const bf16x8* base = (const bf16x8*)cbp;

    auto load_tile = [&](int t, bf16x8* ch, bf16x8* cl, bf16x8& ca) {
        const bf16x8* bp = base + (size_t)t * 576 + lane;
        #pragma unroll
        for (int c = 0; c < 4; ++c) {
            ch[c] = bp[c * 128];
            cl[c] = bp[c * 128 + 64];
        }
        ca = bp[512];
    };
    auto screen_tile = [&](int t, const bf16x8* ch, const bf16x8* cl, bf16x8 ca) {
        // single accumulator: csum bias + hi*hi + hi*lo + lo*hi
        f32x16 acc = __builtin_amdgcn_mfma_f32_32x32x16_bf16(ca, x4, zacc, 0, 0, 0);
        #pragma unroll
        for (int c = 0; c < 4; ++c)
            acc = __builtin_amdgcn_mfma_f32_32x32x16_bf16(ch[c], xh[c], acc, 0, 0, 0);
        #pragma unroll
        for (int c = 0; c < 4; ++c)
            acc = __builtin_amdgcn_mfma_f32_32x32x16_bf16(ch[c], xl[c], acc, 0, 0, 0);
        #pragma unroll
        for (int c = 0; c < 4; ++c)
            acc = __builtin_amdgcn_mfma_f32_32x32x16_bf16(cl[c], xh[c], acc, 0, 0, 0);
        // within-tile top-2 + first-argmax: 4 VALU/value (med3, cmp, cnd, fmax)
        float vl = -3e38f, sl = -3e38f;
        int kl = 0;
        #pragma unroll
        for (int r = 0; r < 16; ++r) {
            float v = acc[r];
            sl = __builtin_amdgcn_fmed3f(v, sl, vl);   // = max(sl, min(vl_old, v))
            bool c2 = v > vl;                           // strict >: first-max
            kl = c2 ? RC[r] : kl;                       // inline-const cndmask
            vl = fmaxf(vl, v);
        }
        // per-tile merge into global (m1, m2, i1) — comparison-exact
        int k = (t << 5) + rh4 + kl;
        bool cg = vl > m1;                              // strict: earlier tile wins ties
        i1 = cg ? k : i1;
        float X = cg ? sl : m2;
        m2 = __builtin_amdgcn_fmed3f(vl, X, m1);        // = max(min(m1,vl), X)
        m1 = fmaxf(m1, vl);
        float tlm = fmaxf(vl, __shfl_xor(vl, 32, 64));
        if (half == 0) tmax[t * PTS_BLK + pb] = tlm;
    };

    bf16x8 chA[4], clA[4], caA, chB[4], clB[4], caB;
    const int t0 = thalf << 4;
    load_tile(t0, chA, clA, caA);
    for (int t = t0; t < t0 + 16; t += 2) {   // double-buffered tile loop
        load_tile(t + 1, chB, clB, caB);
        screen_tile(t, chA, clA, caA);
        if (t + 2 < t0 + 16) load_tile(t + 2, chA, clA, caA);
        screen_tile(t + 1, chB, clB, caB);
    }
    // cross-half merge; ties resolve via ambiguous path
    {
        float m1o = __shfl_xor(m1, 32, 64);
        float m2o = __shfl_xor(m2, 32, 64);
        int   i1o = __shfl_xor(i1, 32, 64);
        m2 = fmaxf(fmaxf(m2, m2o), fminf(m1, m1o));
        i1 = (m1o > m1) ? i1o : i1;
        m1 = fmaxf(m1, m1o);
        if (half == 0) {
            m1s[wave * 32 + l31] = m1;
            m2s[wave * 32 + l31] = m2;
            i1s[wave * 32 + l31] = i1;
        }
    }
    __syncthreads();
    // wave-pair merge: top-2 of union; wave A (lower tiles) wins ties -> lower k
    if (tid < PTS_BLK) {
        int p = tid, l = p & 31, wA = (p >> 5) * 2;
        float a1 = m1s[wA * 32 + l], a2 = m2s[wA * 32 + l];
        float b1 = m1s[wA * 32 + 32 + l], b2 = m2s[wA * 32 + 32 + l];
        int   ai = i1s[wA * 32 + l],  bi = i1s[wA * 32 + 32 + l];
        bool cg = b1 > a1;
        float mm1 = fmaxf(a1, b1);
        float mm2 = __builtin_amdgcn_fmed3f(a1, b1, cg ? b2 : a2);
        m1f[p] = mm1;
        fk[p]  = cg ? bi : ai;
        if (mm2 >= mm1 - EPS_A_W) {
            int a = atomicAdd(&acount, 1);
            ambig[a] = p;
        }
    }
    __syncthreads();

    // Exact rescan: one wave per ambiguous point, candidate tiles only.
    // Reference-bit-exact: dist = fl32(fl32(A+csum[k]) - fl32(2*seqFMA)).
    for (int a = wave; a < acount; a += 4) {
        int p = ambig[a];
        const float* xrow = &xs[p * 65];
        float Aq = np_pairwise_sumsq64(xrow);
        float thr = m1f[p] - EPS_T_W;
        unsigned long long best = ~0ULL;
        for (int t = 0; t < 32; ++t) {
            if (tmax[t * PTS_BLK + p] < thr) continue;   // wave-uniform branch
            if (lane < 32) {
                int k = (t << 5) + lane;
                const float* crow = cb + (size_t)k * 64;
                float m = 0.0f;
                #pragma unroll
                for (int d = 0; d < 64; ++d) m = __fmaf_rn(xrow[d], crow[d], m);
                float D = __fsub_rn(__fadd_rn(Aq, csum[k]), __fmul_rn(2.0f, m));
                unsigned long long key =
                    ((unsigned long long)__float_as_uint(D) << 10) | (unsigned)k;
                best = (key < best) ? key : best;
            }
        }
        #pragma unroll
        for (int off = 32; off > 0; off >>= 1) {
            unsigned long long o = __shfl_xor(best, off, 64);
            best = (o < best) ? o : best;
        }
        if (lane == 0) fk[p] = (int)(best & 1023ULL);
    }
    __syncthreads();

    // indices + histogram
    if (tid < PTS_BLK) {
        int myk = fk[tid];
        out[OUT_I_OFF + n0 + tid] = (float)myk;
        atomicAdd(&hist[myk], 1u);
    }
    // Fused stage+SSE: read each selected cb row ONCE row-coalesced (float4),
    // accumulate f64 SSE against x in xs, overwrite xs with q for write-out.
    double e = 0.0;
    #pragma unroll
    for (int i2 = 0; i2 < 4; ++i2) {
        int i = tid + i2 * 256;               // 0..1023
        int p = i >> 4, seg = i & 15;
        const float4 q = *(const float4*)(cb + (size_t)fk[p] * 64 + seg * 4);
        float* xp = &xs[p * 65 + seg * 4];    // stride-65: only 4B aligned -> scalar ops
        float x0 = xp[0], x1 = xp[1], x2 = xp[2], x3 = xp[3];
        double d0 = (double)x0 - (double)q.x; e = fma(d0, d0, e);
        double d1 = (double)x1 - (double)q.y; e = fma(d1, d1, e);
        double d2 = (double)x2 - (double)q.z; e = fma(d2, d2, e);
        double d3 = (double)x3 - (double)q.w; e = fma(d3, d3, e);
        xp[0] = q.x; xp[1] = q.y; xp[2] = q.z; xp[3] = q.w;
    }
    #pragma unroll
    for (int off = 32; off > 0; off >>= 1) e += __shfl_down(e, off, 64);
    if (lane == 0) wred[wave] = e;
    __syncthreads();
    if (tid == 0) {
        double s = 0.0;
        #pragma unroll
        for (int w = 0; w < 4; ++w) s += wred[w];
        atomicAdd(sse, s);
    }
    // quantized [B,C,H,W]: coalesced 64-float store rows per c, from staged xs
    for (int i = tid; i < PTS_BLK * 64; i += 256) {
        int p = i & (PTS_BLK - 1), c = i >> 6;
        out[OUT_Q_OFF + (size_t)b * 65536 + (size_t)c * HW + hw0 + p] = xs[p * 65 + c];
    }

    // Last-block finalize (replaces vq_final kernel): release via threadfence,
    // count blocks, winner reads hist/sse with agent-scope atomic loads
    // (cross-XCD L2s are not coherent for plain loads).
    __threadfence();
    __syncthreads();
    if (tid == 0)
        isLast = (atomicAdd(done, 1u) == (unsigned)(gridDim.x - 1)) ? 1 : 0;
    __syncthreads();
    if (isLast) {
        double s = 0.0;
        for (int i = tid; i < K_CODES; i += 256) {
            unsigned int h = __hip_atomic_load(&hist[i], __ATOMIC_RELAXED,
                                               __HIP_MEMORY_SCOPE_AGENT);
            double pr = (double)h / (double)N_PTS;
            s += pr * log(pr + 1e-10);
        }
        #pragma unroll
        for (int off = 32; off > 0; off >>= 1) s += __shfl_down(s, off, 64);
        if (lane == 0) wred[wave] = s;
        __syncthreads();
        if (tid == 0) {
            double st = 0.0;
            #pragma unroll
            for (int w = 0; w < 4; ++w) st += wred[w];
            double sv = __hip_atomic_load(sse, __ATOMIC_RELAXED,
                                          __HIP_MEMORY_SCOPE_AGENT);
            out[OUT_P_OFF] = (float)exp(-st);
            out[0] = (float)(1.25 * sv / (double)Q_ELEMS);
        }
    }
}

extern "C" void kernel_launch(void* const* d_in, const int* in_sizes, int n_in,
                              void* d_out, int out_size, void* d_ws, size_t ws_size,
                              hipStream_t stream) {
    const float* latents = (const float*)d_in[0];
    const float* cb      = (const float*)d_in[1];
    float* out = (float*)d_out;
    char* ws = (char*)d_ws;

    unsigned int*   hist = (unsigned int*)(ws + WS_HIST);
    double*         sse  = (double*)(ws + WS_SSE);
    unsigned int*   done = (unsigned int*)(ws + WS_DONE);
    float*          csum = (float*)(ws + WS_CSUM);
    unsigned short* cbp  = (unsigned short*)(ws + WS_CBP);

    vq_prep<<<8, 256, 0, stream>>>(cb, csum, cbp, hist, sse, done);
    vq_main<<<N_PTS / PTS_BLK, 256, 0, stream>>>(latents, cb, csum, cbp,
                                                 hist, sse, done, out);
}

// Round 4
// 136.337 us; speedup vs baseline: 2.4643x; 1.7440x over previous
//
#include <hip/hip_runtime.h>

// Problem constants
#define N_PTS   65536      // B*H*W = 64*32*32
#define K_CODES 1024
#define C_DIM   64
#define HW      1024
#define Q_ELEMS 4194304

// d_out layout (float32): [vq_loss(1) | quantized(4194304) | perplexity(1) | indices(65536)]
#define OUT_Q_OFF 1
#define OUT_P_OFF 4194305
#define OUT_I_OFF 4194306

// ws layout (bytes)
#define WS_HIST 0          // 1024 u32    (4096)
#define WS_SSE  4096       // 1 double    (8)
#define WS_CSUM 8192       // 1024 f32    (4096)
#define WS_CBP  16384      // packed A-frags: 32 tiles * 9 slots * 512 shorts = 294912 B

// Screen metric is w = x.c - csum/2 (argmin dist == argmax w). Proven dist-space
// thresholds EPS_A=1.5e-4 / EPS_T=4e-4 map to w-space /2:
#define EPS_A_W 7.5e-5f    // ambiguous if m2 >= m1 - EPS_A_W
#define EPS_T_W 2.0e-4f    // candidate tile if tmax >= m1 - EPS_T_W

typedef float f32x16 __attribute__((ext_vector_type(16)));
typedef short bf16x8 __attribute__((ext_vector_type(8)));

__device__ __forceinline__ unsigned short bf16rn(float f) {
    unsigned int u = __float_as_uint(f);
    return (unsigned short)((u + 0x7FFFu + ((u >> 16) & 1u)) >> 16);
}
__device__ __forceinline__ float bf16tof(unsigned short h) {
    return __uint_as_float(((unsigned int)h) << 16);
}

// numpy pairwise sum (n=64): 8 accumulators striding 8, then pairwise combine.
__device__ __forceinline__ float np_pairwise_sumsq64(const float* a) {
    float r[8];
    #pragma unroll
    for (int j = 0; j < 8; ++j) r[j] = __fmul_rn(a[j], a[j]);
    #pragma unroll
    for (int i = 8; i < 64; i += 8) {
        #pragma unroll
        for (int j = 0; j < 8; ++j)
            r[j] = __fadd_rn(r[j], __fmul_rn(a[i + j], a[i + j]));
    }
    return __fadd_rn(__fadd_rn(__fadd_rn(r[0], r[1]), __fadd_rn(r[2], r[3])),
                     __fadd_rn(__fadd_rn(r[4], r[5]), __fadd_rn(r[6], r[7])));
}

// Prep (2048 threads): csum + codebook packed into MFMA A-frag order.
// Also zeroes hist/sse (kernel boundary publishes before vq_main — no memset
// launch, and crucially NO per-block __threadfence anywhere: on gfx950 an
// agent-scope fence emits buffer_wbl2 (full per-XCD L2 writeback); doing it
// per block serialized ~128 L2 flushes/XCD and cost ~120us in R1-R3).
__global__ void vq_prep(const float* __restrict__ cb, float* __restrict__ csum,
                        unsigned short* __restrict__ cbp,
                        unsigned int* __restrict__ hist,
                        double* __restrict__ sse) {
    int g = blockIdx.x * 256 + threadIdx.x;   // 0..2047
    if (g < 1024) hist[g] = 0u;
    if (g == 1024) *sse = 0.0;
    int t = g >> 6, lane = g & 63, l31 = lane & 31, half = lane >> 5;
    int row = t * 32 + l31;
    const float* r = cb + row * 64;
    float cs = np_pairwise_sumsq64(r);
    if (half == 0) csum[row] = cs;
    size_t tb = (size_t)t * 9 * 512;          // shorts per tile
    #pragma unroll
    for (int c = 0; c < 4; ++c) {
        bf16x8 h8, l8;
        #pragma unroll
        for (int j = 0; j < 8; ++j) {
            float f = r[c * 16 + half * 8 + j];
            unsigned short h = bf16rn(f);
            h8[j] = (short)h;
            l8[j] = (short)bf16rn(f - bf16tof(h));
        }
        *(bf16x8*)(cbp + tb + (size_t)(c * 2 + 0) * 512 + lane * 8) = h8;
        *(bf16x8*)(cbp + tb + (size_t)(c * 2 + 1) * 512 + lane * 8) = l8;
    }
    bf16x8 c8;
    #pragma unroll
    for (int j = 0; j < 8; ++j) c8[j] = 0;
    if (half == 0) c8[0] = (short)bf16rn(-0.5f * cs);
    *(bf16x8*)(cbp + tb + (size_t)8 * 512 + lane * 8) = c8;
}

// Main: block = 128 points, 8 waves (512 thr). Wave = (point-group, tile-half):
// grp = wave>>1 owns 32 points, thalf = wave&1 screens tiles [thalf*16, +16).
// Grid = 512 blocks = 2 blocks/CU x 8 waves = 16 waves/CU (4/SIMD) — double
// R0's residency with IDENTICAL per-CU work. launch_bounds (512,2): measured
// gfx950 cap law is arch-VGPR cap = 256/min_waves ((256,2)->88 ok @R0/R3;
// (512,4)/(256,4)->64, tile frags spill to scratch, 4x slower @R1/R2). (512,2)
// caps at 128 >= natural 88 -> no spill. NO __threadfence / device finalize:
// per-block agent fences = serialized per-XCD L2 writebacks (~120us, R3 bug).
// Screen: ONE MFMA accumulator (csum bias + hi*hi + hi*lo + lo*hi; reorder
// error ~5e-8 << EPS_A_W) + med3-based top-2 (validated R1-R3, passed).
__global__ __launch_bounds__(512, 2) void vq_main(
        const float* __restrict__ latents,
        const float* __restrict__ cb,
        const float* __restrict__ csum,
        const unsigned short* __restrict__ cbp,
        unsigned int* __restrict__ hist,
        double* __restrict__ sse,
        float* __restrict__ out) {
    __shared__ float xs[128 * 65];            // 33.3 KB, stride 65 (x, then q)
    __shared__ float tmax[32 * 128];          // 16 KB per-(tile,point) screen max
    __shared__ float m1s[8 * 32], m2s[8 * 32];
    __shared__ int   i1s[8 * 32];
    __shared__ float m1f[128];
    __shared__ int   fk[128], ambig[128], acount;
    __shared__ double wred[8];

    const int tid  = threadIdx.x;
    const int lane = tid & 63, wave = tid >> 6;   // wave 0..7
    const int grp = wave >> 1, thalf = wave & 1;
    const int n0 = blockIdx.x * 128;
    const int b = n0 >> 10, hw0 = n0 & 1023;
    const float* xg = latents + (size_t)b * C_DIM * HW + hw0;

    for (int i = tid; i < 128 * 64; i += 512) {
        int p = i & 127, d = i >> 7;
        xs[p * 65 + d] = xg[(size_t)d * HW + p];
    }
    if (tid == 0) acount = 0;
    __syncthreads();

    // B-frags: col = lane&31 -> point, k = (lane>>5)*8 + j
    const int l31 = lane & 31, half = lane >> 5;
    const int pb = (grp << 5) + l31;
    bf16x8 xh[4], xl[4], x4;
    #pragma unroll
    for (int c = 0; c < 4; ++c)
        #pragma unroll
        for (int j = 0; j < 8; ++j) {
            float f = xs[pb * 65 + c * 16 + half * 8 + j];
            unsigned short h = bf16rn(f);
            xh[c][j] = (short)h;
            xl[c][j] = (short)bf16rn(f - bf16tof(h));
        }
    #pragma unroll
    for (int j = 0; j < 8; ++j) x4[j] = 0;
    if (half == 0) x4[0] = (short)0x3F80;     // bf16(1.0) at k=64

    // loop-invariant zero C-operand: first MFMA of each tile reads ZERO and
    // fully overwrites acc -> no per-tile 16-mov zero-init.
    f32x16 zacc;
    #pragma unroll
    for (int r = 0; r < 16; ++r) zacc[r] = 0.0f;

    float m1 = -3e38f, m2 = -3e38f;
    int i1 = 0;
    const int RC[16] = {0,1,2,3,8,9,10,11,16,17,18,19,24,25,26,27};
    const int rh4 = half * 4;
    const bf16x8* base = (const bf16x8*)cbp;

    auto load_tile = [&](int t, bf16x8* ch, bf16x8* cl, bf16x8& ca) {
        const bf16x8* bp = base + (size_t)t * 576 + lane;
        #pragma unroll
        for (int c = 0; c < 4; ++c) {
            ch[c] = bp[c * 128];
            cl[c] = bp[c * 128 + 64];
        }
        ca = bp[512];
    };
    auto screen_tile = [&](int t, const bf16x8* ch, const bf16x8* cl, bf16x8 ca) {
        // single accumulator: csum bias + hi*hi + hi*lo + lo*hi
        f32x16 acc = __builtin_amdgcn_mfma_f32_32x32x16_bf16(ca, x4, zacc, 0, 0, 0);
        #pragma unroll
        for (int c = 0; c < 4; ++c)
            acc = __builtin_amdgcn_mfma_f32_32x32x16_bf16(ch[c], xh[c], acc, 0, 0, 0);
        #pragma unroll
        for (int c = 0; c < 4; ++c)
            acc = __builtin_amdgcn_mfma_f32_32x32x16_bf16(ch[c], xl[c], acc, 0, 0, 0);
        #pragma unroll
        for (int c = 0; c < 4; ++c)
            acc = __builtin_amdgcn_mfma_f32_32x32x16_bf16(cl[c], xh[c], acc, 0, 0, 0);
        // within-tile top-2 + first-argmax: 4 VALU/value (med3, cmp, cnd, fmax)
        float vl = -3e38f, sl = -3e38f;
        int kl = 0;
        #pragma unroll
        for (int r = 0; r < 16; ++r) {
            float v = acc[r];
            sl = __builtin_amdgcn_fmed3f(v, sl, vl);   // = max(sl, min(vl_old, v))
            bool c2 = v > vl;                           // strict >: first-max
            kl = c2 ? RC[r] : kl;                       // inline-const cndmask
            vl = fmaxf(vl, v);
        }
        // per-tile merge into global (m1, m2, i1) — comparison-exact
        int k = (t << 5) + rh4 + kl;
        bool cg = vl > m1;                              // strict: earlier tile wins ties
        i1 = cg ? k : i1;
        float X = cg ? sl : m2;
        m2 = __builtin_amdgcn_fmed3f(vl, X, m1);        // = max(min(m1,vl), X)
        m1 = fmaxf(m1, vl);
        float tlm = fmaxf(vl, __shfl_xor(vl, 32, 64));
        if (half == 0) tmax[t * 128 + pb] = tlm;
    };

    bf16x8 chA[4], clA[4], caA, chB[4], clB[4], caB;
    const int t0 = thalf << 4;
    load_tile(t0, chA, clA, caA);
    for (int t = t0; t < t0 + 16; t += 2) {   // double-buffered tile loop
        load_tile(t + 1, chB, clB, caB);
        screen_tile(t, chA, clA, caA);
        if (t + 2 < t0 + 16) load_tile(t + 2, chA, clA, caA);
        screen_tile(t + 1, chB, clB, caB);
    }
    // cross-half merge; ties resolve via ambiguous path
    {
        float m1o = __shfl_xor(m1, 32, 64);
        float m2o = __shfl_xor(m2, 32, 64);
        int   i1o = __shfl_xor(i1, 32, 64);
        m2 = fmaxf(fmaxf(m2, m2o), fminf(m1, m1o));
        i1 = (m1o > m1) ? i1o : i1;
        m1 = fmaxf(m1, m1o);
        if (half == 0) {
            m1s[wave * 32 + l31] = m1;
            m2s[wave * 32 + l31] = m2;
            i1s[wave * 32 + l31] = i1;
        }
    }
    __syncthreads();
    // wave-pair merge: top-2 of union; wave A (lower tiles) wins ties -> lower k
    if (tid < 128) {
        int p = tid, l = p & 31, wA = (p >> 5) * 2;
        float a1 = m1s[wA * 32 + l], a2 = m2s[wA * 32 + l];
        float b1 = m1s[wA * 32 + 32 + l], b2 = m2s[wA * 32 + 32 + l];
        int   ai = i1s[wA * 32 + l],  bi = i1s[wA * 32 + 32 + l];
        bool cg = b1 > a1;
        float mm1 = fmaxf(a1, b1);
        float mm2 = __builtin_amdgcn_fmed3f(a1, b1, cg ? b2 : a2);
        m1f[p] = mm1;
        fk[p]  = cg ? bi : ai;
        if (mm2 >= mm1 - EPS_A_W) {
            int a = atomicAdd(&acount, 1);
            ambig[a] = p;
        }
    }
    __syncthreads();

    // Exact rescan: one wave per ambiguous point, candidate tiles only.
    // Reference-bit-exact: dist = fl32(fl32(A+csum[k]) - fl32(2*seqFMA)).
    for (int a = wave; a < acount; a += 8) {
        int p = ambig[a];
        const float* xrow = &xs[p * 65];
        float Aq = np_pairwise_sumsq64(xrow);
        float thr = m1f[p] - EPS_T_W;
        unsigned long long best = ~0ULL;
        for (int t = 0; t < 32; ++t) {
            if (tmax[t * 128 + p] < thr) continue;   // wave-uniform branch
            if (lane < 32) {
                int k = (t << 5) + lane;
                const float* crow = cb + (size_t)k * 64;
                float m = 0.0f;
                #pragma unroll
                for (int d = 0; d < 64; ++d) m = __fmaf_rn(xrow[d], crow[d], m);
                float D = __fsub_rn(__fadd_rn(Aq, csum[k]), __fmul_rn(2.0f, m));
                unsigned long long key =
                    ((unsigned long long)__float_as_uint(D) << 10) | (unsigned)k;
                best = (key < best) ? key : best;
            }
        }
        #pragma unroll
        for (int off = 32; off > 0; off >>= 1) {
            unsigned long long o = __shfl_xor(best, off, 64);
            best = (o < best) ? o : best;
        }
        if (lane == 0) fk[p] = (int)(best & 1023ULL);
    }
    __syncthreads();

    // indices + histogram
    if (tid < 128) {
        int myk = fk[tid];
        out[OUT_I_OFF + n0 + tid] = (float)myk;
        atomicAdd(&hist[myk], 1u);
    }
    // Fused stage+SSE: read each selected cb row ONCE row-coalesced (float4),
    // accumulate f64 SSE against x in xs, overwrite xs with q for write-out.
    double e = 0.0;
    #pragma unroll
    for (int i2 = 0; i2 < 4; ++i2) {
        int i = tid + i2 * 512;               // 0..2047
        int p = i >> 4, seg = i & 15;
        const float4 q = *(const float4*)(cb + (size_t)fk[p] * 64 + seg * 4);
        float* xp = &xs[p * 65 + seg * 4];    // stride-65: only 4B aligned -> scalar ops
        float x0 = xp[0], x1 = xp[1], x2 = xp[2], x3 = xp[3];
        double d0 = (double)x0 - (double)q.x; e = fma(d0, d0, e);
        double d1 = (double)x1 - (double)q.y; e = fma(d1, d1, e);
        double d2 = (double)x2 - (double)q.z; e = fma(d2, d2, e);
        double d3 = (double)x3 - (double)q.w; e = fma(d3, d3, e);
        xp[0] = q.x; xp[1] = q.y; xp[2] = q.z; xp[3] = q.w;
    }
    #pragma unroll
    for (int off = 32; off > 0; off >>= 1) e += __shfl_down(e, off, 64);
    if (lane == 0) wred[wave] = e;
    __syncthreads();
    if (tid == 0) {
        double s = 0.0;
        #pragma unroll
        for (int w = 0; w < 8; ++w) s += wred[w];
        atomicAdd(sse, s);
    }
    // quantized [B,C,H,W]: coalesced 128-float store rows per c, from staged xs
    for (int i = tid; i < 128 * 64; i += 512) {
        int p = i & 127, c = i >> 7;
        out[OUT_Q_OFF + (size_t)b * 65536 + (size_t)c * HW + hw0 + p] = xs[p * 65 + c];
    }
}

// Finalize: perplexity from histogram, vq_loss from SSE. Separate launch —
// the kernel boundary provides device-wide visibility of hist/sse without
// any per-block L2-writeback fence.
__global__ void vq_final(const unsigned int* __restrict__ hist,
                         const double* __restrict__ sse,
                         float* __restrict__ out) {
    __shared__ double red[256];
    int t = threadIdx.x;
    double s = 0.0;
    for (int i = t; i < K_CODES; i += 256) {
        double p = (double)hist[i] / (double)N_PTS;
        s += p * log(p + 1e-10);
    }
    red[t] = s;
    __syncthreads();
    for (int w = 128; w > 0; w >>= 1) {
        if (t < w) red[t] += red[t + w];
        __syncthreads();
    }
    if (t == 0) {
        out[OUT_P_OFF] = (float)exp(-red[0]);
        out[0] = (float)(1.25 * sse[0] / (double)Q_ELEMS);
    }
}

extern "C" void kernel_launch(void* const* d_in, const int* in_sizes, int n_in,
                              void* d_out, int out_size, void* d_ws, size_t ws_size,
                              hipStream_t stream) {
    const float* latents = (const float*)d_in[0];
    const float* cb      = (const float*)d_in[1];
    float* out = (float*)d_out;
    char* ws = (char*)d_ws;

    unsigned int*   hist = (unsigned int*)(ws + WS_HIST);
    double*         sse  = (double*)(ws + WS_SSE);
    float*          csum = (float*)(ws + WS_CSUM);
    unsigned short* cbp  = (unsigned short*)(ws + WS_CBP);

    vq_prep <<<8, 256, 0, stream>>>(cb, csum, cbp, hist, sse);
    vq_main <<<N_PTS / 128, 512, 0, stream>>>(latents, cb, csum, cbp,
                                              hist, sse, out);
    vq_final<<<1, 256, 0, stream>>>(hist, sse, out);
}